// Round 1
// baseline (5545.589 us; speedup 1.0000x reference)
//
#include <hip/hip_runtime.h>
#include <hip/hip_bf16.h>

#define S 2048
#define NEGV -10000.0f

typedef unsigned long long ull;

__device__ __forceinline__ float fsig(float x) {
  return 1.0f / (1.0f + __expf(-x));
}
__device__ __forceinline__ float ftanh(float x) {
  float a = fabsf(x);
  float e = __expf(-2.0f * a);
  float r = (1.0f - e) / (1.0f + e);
  return copysignf(r, x);
}

// ---------------- init: seed h0 with stamp 1, invalidate other slot ----------------
__global__ void init_h_k(const float* __restrict__ h0, ull* __restrict__ hbuf) {
  int dir = blockIdx.x;          // 0,1
  int u = threadIdx.x;           // 0..511
  ull pk = (1ULL << 32) | (ull)__float_as_uint(h0[dir * 512 + u]);
  __hip_atomic_store(&hbuf[dir * 1024 + u], pk, __ATOMIC_RELAXED, __HIP_MEMORY_SCOPE_AGENT);
  __hip_atomic_store(&hbuf[dir * 1024 + 512 + u], 0ULL, __ATOMIC_RELAXED, __HIP_MEMORY_SCOPE_AGENT);
}

// ---------------- xg GEMM: xg[m][n] = emb[sent[m]] . Wrow(n) + bias(n) ----------------
// n < 2048 -> Wih_f row n (+bih_f+bhh_f), else Wih_b row n-2048 (+bih_b+bhh_b)
__global__ __launch_bounds__(256) void gemm_xg_k(
    const int* __restrict__ sent, const float* __restrict__ emb,
    const float* __restrict__ Wih_f, const float* __restrict__ Wih_b,
    const float* __restrict__ bih_f, const float* __restrict__ bhh_f,
    const float* __restrict__ bih_b, const float* __restrict__ bhh_b,
    float* __restrict__ xg)
{
  __shared__ __align__(16) float Asm[64 * 36];   // [64][36] pad
  __shared__ __align__(16) float Bsm[32 * 68];   // [32][68] pad, B[kk][n]
  __shared__ int sidx[64];

  const int bx = blockIdx.x;     // N tile 0..63
  const int by = blockIdx.y;     // M tile 0..31
  const int t = threadIdx.x;
  const int n0 = bx * 64, m0 = by * 64;

  const float* W = (n0 < 2048) ? (Wih_f + (size_t)n0 * 1024)
                               : (Wih_b + (size_t)(n0 - 2048) * 1024);
  if (t < 64) sidx[t] = sent[m0 + t];
  __syncthreads();

  const int tm = t >> 4, tn = t & 15;
  const int lr = t >> 2, lkq = t & 3;   // loader: row, k-quarter (8 floats)
  float acc[4][4] = {};

  for (int k0 = 0; k0 < 1024; k0 += 32) {
    const float* ap = emb + (size_t)sidx[lr] * 1024 + k0 + lkq * 8;
    float4 a0 = *(const float4*)ap;
    float4 a1 = *(const float4*)(ap + 4);
    const float* bp = W + (size_t)lr * 1024 + k0 + lkq * 8;
    float4 b0 = *(const float4*)bp;
    float4 b1 = *(const float4*)(bp + 4);
    __syncthreads();   // prior compute done before LDS overwrite
    *(float4*)&Asm[lr * 36 + lkq * 8]     = a0;
    *(float4*)&Asm[lr * 36 + lkq * 8 + 4] = a1;
    {
      const float* bb0 = (const float*)&b0;
      const float* bb1 = (const float*)&b1;
      #pragma unroll
      for (int j = 0; j < 4; ++j) Bsm[(lkq * 8 + j) * 68 + lr] = bb0[j];
      #pragma unroll
      for (int j = 0; j < 4; ++j) Bsm[(lkq * 8 + 4 + j) * 68 + lr] = bb1[j];
    }
    __syncthreads();
    #pragma unroll
    for (int kk = 0; kk < 32; ++kk) {
      float a0_ = Asm[(tm * 4 + 0) * 36 + kk];
      float a1_ = Asm[(tm * 4 + 1) * 36 + kk];
      float a2_ = Asm[(tm * 4 + 2) * 36 + kk];
      float a3_ = Asm[(tm * 4 + 3) * 36 + kk];
      float4 bv = *(const float4*)&Bsm[kk * 68 + tn * 4];
      acc[0][0] = fmaf(a0_, bv.x, acc[0][0]); acc[0][1] = fmaf(a0_, bv.y, acc[0][1]);
      acc[0][2] = fmaf(a0_, bv.z, acc[0][2]); acc[0][3] = fmaf(a0_, bv.w, acc[0][3]);
      acc[1][0] = fmaf(a1_, bv.x, acc[1][0]); acc[1][1] = fmaf(a1_, bv.y, acc[1][1]);
      acc[1][2] = fmaf(a1_, bv.z, acc[1][2]); acc[1][3] = fmaf(a1_, bv.w, acc[1][3]);
      acc[2][0] = fmaf(a2_, bv.x, acc[2][0]); acc[2][1] = fmaf(a2_, bv.y, acc[2][1]);
      acc[2][2] = fmaf(a2_, bv.z, acc[2][2]); acc[2][3] = fmaf(a2_, bv.w, acc[2][3]);
      acc[3][0] = fmaf(a3_, bv.x, acc[3][0]); acc[3][1] = fmaf(a3_, bv.y, acc[3][1]);
      acc[3][2] = fmaf(a3_, bv.z, acc[3][2]); acc[3][3] = fmaf(a3_, bv.w, acc[3][3]);
    }
  }

  const float* bi = (n0 < 2048) ? bih_f : bih_b;
  const float* bh = (n0 < 2048) ? bhh_f : bhh_b;
  const int nb = (n0 < 2048) ? n0 : (n0 - 2048);
  #pragma unroll
  for (int i = 0; i < 4; ++i) {
    int m = m0 + tm * 4 + i;
    #pragma unroll
    for (int j = 0; j < 4; ++j) {
      int nn = tn * 4 + j;
      float bias = bi[nb + nn] + bh[nb + nn];
      xg[(size_t)m * 4096 + n0 + nn] = acc[i][j] + bias;
    }
  }
}

// ---------------- persistent bidirectional LSTM recurrence ----------------
// grid = 128 WGs x 256 thr. dir = wg&1, wid = wg>>1 (owns hidden units wid*8..+7).
// h exchanged via packed (stamp<<32 | f32bits) 8B agent-scope atomics, parity slots.
__global__ __launch_bounds__(256, 1) void lstm_rec_k(
    const float* __restrict__ Whh_f, const float* __restrict__ Whh_b,
    const float* __restrict__ c0,
    const float* __restrict__ xg,      // [S][4096]
    ull* __restrict__ hbuf,            // [2 dir][2 slot][512]
    float* __restrict__ hs_cat)        // [S][1024]
{
  const int w = blockIdx.x;
  const int dir = w & 1;
  const int wid = w >> 1;              // 0..63
  const int t = threadIdx.x;
  const int rr = t >> 3;               // 0..31
  const int seg = t & 7;               // 0..7
  const int g = rr >> 3;               // gate 0..3 (i,f,g,o)
  const int ul = rr & 7;               // local unit 0..7
  const int unit = wid * 8 + ul;       // 0..511
  const int grow = g * 512 + unit;     // global Whh row

  const float* Whh = dir ? Whh_b : Whh_f;

  float wreg[64];
  {
    const float* src = Whh + (size_t)grow * 512 + seg * 64;
    #pragma unroll
    for (int j = 0; j < 16; ++j) {
      float4 v = *(const float4*)(src + j * 4);
      wreg[4 * j + 0] = v.x; wreg[4 * j + 1] = v.y;
      wreg[4 * j + 2] = v.z; wreg[4 * j + 3] = v.w;
    }
  }

  __shared__ __align__(16) float h_lds[512];
  __shared__ float gate_lds[32];

  ull* hb = hbuf + dir * 1024;

  float c_reg = 0.0f;
  if (t < 8) c_reg = c0[dir * 512 + wid * 8 + t];

  const int u0 = t * 2, u1 = t * 2 + 1;

  for (int k = 0; k < S; ++k) {
    // prefetch this step's xg value (owner lane per gate-row)
    float xgv = 0.0f;
    if (seg == 0) {
      int rowk = dir ? (S - 1 - k) : k;
      xgv = xg[(size_t)rowk * 4096 + dir * 2048 + grow];
    }
    // poll h_{k}: stamp k+1 in slot k&1 (data fused with stamp -> no fences)
    {
      ull* src = hb + (k & 1) * 512;
      const unsigned want = (unsigned)(k + 1);
      ull a = __hip_atomic_load(&src[u0], __ATOMIC_RELAXED, __HIP_MEMORY_SCOPE_AGENT);
      ull b = __hip_atomic_load(&src[u1], __ATOMIC_RELAXED, __HIP_MEMORY_SCOPE_AGENT);
      while ((unsigned)(a >> 32) != want)
        a = __hip_atomic_load(&src[u0], __ATOMIC_RELAXED, __HIP_MEMORY_SCOPE_AGENT);
      while ((unsigned)(b >> 32) != want)
        b = __hip_atomic_load(&src[u1], __ATOMIC_RELAXED, __HIP_MEMORY_SCOPE_AGENT);
      h_lds[u0] = __uint_as_float((unsigned)a);
      h_lds[u1] = __uint_as_float((unsigned)b);
    }
    __syncthreads();
    // partial dot: this thread's 64-wide segment of row `grow`
    float p0 = 0.f, p1 = 0.f, p2 = 0.f, p3 = 0.f;
    const float4* h4 = (const float4*)(h_lds + seg * 64);
    #pragma unroll
    for (int j = 0; j < 16; ++j) {
      float4 hv = h4[j];
      p0 = fmaf(wreg[4 * j + 0], hv.x, p0);
      p1 = fmaf(wreg[4 * j + 1], hv.y, p1);
      p2 = fmaf(wreg[4 * j + 2], hv.z, p2);
      p3 = fmaf(wreg[4 * j + 3], hv.w, p3);
    }
    float p = (p0 + p1) + (p2 + p3);
    p += __shfl_xor(p, 1);
    p += __shfl_xor(p, 2);
    p += __shfl_xor(p, 4);
    if (seg == 0) gate_lds[rr] = p + xgv;
    __syncthreads();
    if (t < 8) {
      float gi = gate_lds[0 * 8 + t];
      float gf = gate_lds[1 * 8 + t];
      float gg = gate_lds[2 * 8 + t];
      float go = gate_lds[3 * 8 + t];
      float iv = fsig(gi), fv = fsig(gf), ov = fsig(go);
      float gv = ftanh(gg);
      c_reg = fv * c_reg + iv * gv;
      float hv = ov * ftanh(c_reg);
      int orig = dir ? (S - 1 - k) : k;
      hs_cat[(size_t)orig * 1024 + dir * 512 + wid * 8 + t] = hv;
      ull pk = ((ull)(unsigned)(k + 2) << 32) | (ull)__float_as_uint(hv);
      __hip_atomic_store(&hb[((k + 1) & 1) * 512 + wid * 8 + t], pk,
                         __ATOMIC_RELAXED, __HIP_MEMORY_SCOPE_AGENT);
    }
    // next iteration's syncthreads(#1) protects gate_lds/h_lds reuse
  }
}

// ---------------- feats[t][j] = hs_cat[t] . Wout[j] + bout[j] ----------------
__global__ __launch_bounds__(64) void feats_k(
    const float* __restrict__ hs_cat, const float* __restrict__ Wout,
    const float* __restrict__ bout, float* __restrict__ feats)
{
  int tpos = blockIdx.x;
  int l = threadIdx.x;
  int j = l & 15, q = l >> 4;
  const float* h = hs_cat + (size_t)tpos * 1024 + q * 256;
  const float* wv = Wout + (size_t)j * 1024 + q * 256;
  float s = 0.f;
  #pragma unroll 8
  for (int i = 0; i < 256; i += 4) {
    float4 hv = *(const float4*)(h + i);
    float4 ww = *(const float4*)(wv + i);
    s = fmaf(hv.x, ww.x, s); s = fmaf(hv.y, ww.y, s);
    s = fmaf(hv.z, ww.z, s); s = fmaf(hv.w, ww.w, s);
  }
  s += __shfl_xor(s, 16);
  s += __shfl_xor(s, 32);
  if (q == 0) feats[tpos * 16 + j] = s + bout[j];
}

// ---------------- Viterbi: single wave, LDS-chunked feats, 4-bit backpointers ----------------
__global__ __launch_bounds__(64, 1) void viterbi_k(
    const float* __restrict__ feats, const float* __restrict__ trans,
    float* __restrict__ out)
{
  __shared__ __align__(16) float fch[2][256 * 16];  // 2 x 16KB double-buffer
  __shared__ unsigned char bp4[S * 8];              // 16KB packed nibbles
  __shared__ float v_lds[16];

  const int l = threadIdx.x;
  const int next = l & 15, q = l >> 4;

  float tr0 = trans[next * 16 + q * 4 + 0];
  float tr1 = trans[next * 16 + q * 4 + 1];
  float tr2 = trans[next * 16 + q * 4 + 2];
  float tr3 = trans[next * 16 + q * 4 + 3];

  if (l < 16) v_lds[l] = (l == 0) ? 0.0f : NEGV;   // START = 0

  const float4* f4 = (const float4*)feats;
  float4 buf[16];
  #pragma unroll
  for (int i = 0; i < 16; ++i) buf[i] = f4[i * 64 + l];
  #pragma unroll
  for (int i = 0; i < 16; ++i) ((float4*)fch[0])[i * 64 + l] = buf[i];
  __syncthreads();

  for (int c = 0; c < 8; ++c) {
    if (c < 7) {
      #pragma unroll
      for (int i = 0; i < 16; ++i) buf[i] = f4[(c + 1) * 1024 + i * 64 + l];
    }
    const float* fc = fch[c & 1];
    for (int tt = 0; tt < 256; ++tt) {
      int t = c * 256 + tt;
      float m = v_lds[q * 4 + 0] + tr0; int mi = q * 4;
      float s1 = v_lds[q * 4 + 1] + tr1; if (s1 > m) { m = s1; mi = q * 4 + 1; }
      float s2 = v_lds[q * 4 + 2] + tr2; if (s2 > m) { m = s2; mi = q * 4 + 2; }
      float s3 = v_lds[q * 4 + 3] + tr3; if (s3 > m) { m = s3; mi = q * 4 + 3; }
      #pragma unroll
      for (int mask = 16; mask <= 32; mask <<= 1) {
        float om = __shfl_xor(m, mask);
        int omi = __shfl_xor(mi, mask);
        if (om > m || (om == m && omi < mi)) { m = om; mi = omi; }
      }
      int pmi = __shfl_xor(mi, 1);
      __syncthreads();   // all lanes done reading v_lds
      if (q == 0) {
        v_lds[next] = m + fc[tt * 16 + next];
        if ((next & 1) == 0)
          bp4[t * 8 + (next >> 1)] = (unsigned char)((mi & 15) | ((pmi & 15) << 4));
      }
      __syncthreads();
    }
    if (c < 7) {
      #pragma unroll
      for (int i = 0; i < 16; ++i) ((float4*)fch[(c + 1) & 1])[i * 64 + l] = buf[i];
      __syncthreads();
    }
  }

  // terminal = v + trans[STOP=1][:]
  float term = (l < 16) ? (v_lds[l] + trans[1 * 16 + l]) : -3.0e38f;
  int ti = (l < 16) ? l : 0;
  #pragma unroll
  for (int mask = 1; mask <= 32; mask <<= 1) {
    float om = __shfl_xor(term, mask);
    int omi = __shfl_xor(ti, mask);
    if (om > term || (om == term && omi < ti)) { term = om; ti = omi; }
  }
  if (l == 0) {
    out[0] = term;
    int tag = ti;
    out[1 + (S - 1)] = (float)tag;
    for (int t = S - 1; t >= 1; --t) {
      tag = (bp4[t * 8 + (tag >> 1)] >> ((tag & 1) * 4)) & 15;
      out[t] = (float)tag;   // out[1 + (t-1)]
    }
  }
}

extern "C" void kernel_launch(void* const* d_in, const int* in_sizes, int n_in,
                              void* d_out, int out_size, void* d_ws, size_t ws_size,
                              hipStream_t stream) {
  const int*   sent  = (const int*)d_in[0];
  const float* emb   = (const float*)d_in[1];
  const float* Wih_f = (const float*)d_in[2];
  const float* Whh_f = (const float*)d_in[3];
  const float* bih_f = (const float*)d_in[4];
  const float* bhh_f = (const float*)d_in[5];
  const float* Wih_b = (const float*)d_in[6];
  const float* Whh_b = (const float*)d_in[7];
  const float* bih_b = (const float*)d_in[8];
  const float* bhh_b = (const float*)d_in[9];
  const float* h0    = (const float*)d_in[10];
  const float* c0    = (const float*)d_in[11];
  const float* Wout  = (const float*)d_in[12];
  const float* bout  = (const float*)d_in[13];
  const float* trans = (const float*)d_in[14];
  float* out = (float*)d_out;

  // workspace layout
  char* ws = (char*)d_ws;
  float* xg     = (float*)(ws);                         // 2048*4096*4 = 32 MiB
  float* hs_cat = (float*)(ws + 33554432);              // 2048*1024*4 = 8 MiB
  float* feats  = (float*)(ws + 41943040);              // 2048*16*4 = 128 KiB
  ull*   hbuf   = (ull*)  (ws + 42074112);              // 2*2*512*8 = 16 KiB

  init_h_k<<<2, 512, 0, stream>>>(h0, hbuf);
  gemm_xg_k<<<dim3(64, 32), 256, 0, stream>>>(sent, emb, Wih_f, Wih_b,
                                              bih_f, bhh_f, bih_b, bhh_b, xg);
  lstm_rec_k<<<128, 256, 0, stream>>>(Whh_f, Whh_b, c0, xg, hbuf, hs_cat);
  feats_k<<<2048, 64, 0, stream>>>(hs_cat, Wout, bout, feats);
  viterbi_k<<<1, 64, 0, stream>>>(feats, trans, out);
}